// Round 1
// 88.811 us; speedup vs baseline: 1.0067x; 1.0067x over previous
//
#include <hip/hip_runtime.h>
#include <hip/hip_fp16.h>
#include <math.h>

// Problem constants (from reference)
#define BATCH    512
#define N_VARS   4096
#define H_ROWS   (2 * N_VARS + 2)   // 8194 encode rows
#define N_OUT1   8192
#define N_OUT3   2048
#define TPB      1024

// Encode-slab layout: per batch-PAIR, uint2[S_U2]; u2[0] = header rows {-inf, 0},
// u2[1+v] = rows {pos_v, neg_v}. As a dword array, dword index == encode row index.
// S_U2 padded to keep 16-B alignment between slabs.
#define S_U2       4100
#define ENC_BYTES  (S_U2 * 8)                 // 32800 B per slab
#define ENC_WS_BYTES ((size_t)(BATCH / 2) * ENC_BYTES)   // 256 slabs
#define R1_BYTES   (N_OUT1 * 8)               // 8192 float2 = 65536
#define SMEM_BYTES (ENC_BYTES + R1_BYTES)     // 98336 B dynamic LDS

// Fast native-transcendental variants. Accuracy budget: threshold 0.38;
// fp32 path measured absmax 0.0625; fp16 encode adds ~0.05-0.1 worst-path.
__device__ __forceinline__ float log1mexp_fast(float x) {
    return __logf(1.0f - __expf(x));
}

__device__ __forceinline__ float2 lse2_fast2(float2 a, float2 b) {
    float2 r;
    r.x = fmaxf(a.x, b.x) + __logf(1.0f + __expf(-fabsf(a.x - b.x)));
    r.y = fmaxf(a.y, b.y) + __logf(1.0f + __expf(-fabsf(a.y - b.y)));
    return r;
}

__device__ __forceinline__ unsigned int h2u(__half2 h) {
    union { __half2 h; unsigned int u; } v; v.h = h; return v.u;
}

// fanin-4 product sum from the fp16 encode table (each __half2 = 2 batch cols).
// Level-1 adds in fp16 (packed), final add in f32 for accuracy.
__device__ __forceinline__ float2 gsum_h(const __half2* __restrict__ enc, int4 q) {
    __half2 v0 = enc[q.x], v1 = enc[q.y], v2 = enc[q.z], v3 = enc[q.w];
    __half2 s01 = __hadd2(v0, v1), s23 = __hadd2(v2, v3);
    float2 f01 = __half22float2(s01), f23 = __half22float2(s23);
    return make_float2(f01.x + f23.x, f01.y + f23.y);
}

// fanin-4 product sum from the f32 r1 table.
__device__ __forceinline__ float2 gsum_f(const float2* __restrict__ rb, int4 q) {
    float2 v0 = rb[q.x], v1 = rb[q.y], v2 = rb[q.z], v3 = rb[q.w];
    return make_float2(v0.x + v1.x + v2.x + v3.x, v0.y + v1.y + v2.y + v3.y);
}

// ---- Prep kernel: fused {transpose + encode(log1mexp) + fp16 pack} AND
// gather-table build in ONE dispatch.
// blocks [0, NTRANS): 32x32 tiles of x[4096][512] -> encE[pair][row] (half2 pairs)
// blocks [NTRANS, NTRANS+NTAB): tab build (flat 256 threads/block)
#define TDIM    32
#define NTRANS  ((BATCH / TDIM) * (N_VARS / TDIM))   // 16 * 128 = 2048
#define NTAB    ((N_OUT1 + N_OUT3) / 256)            // 40
__global__ void prep_kernel(const float* __restrict__ x,
                            uint2* __restrict__ encE,
                            const int* __restrict__ p0,
                            const int* __restrict__ p1,
                            const int* __restrict__ p2,
                            const int* __restrict__ p3,
                            int4* __restrict__ tabB,
                            int4* __restrict__ tabC) {
    __shared__ float tile[TDIM][TDIM + 1];
    int blk = blockIdx.x;
    int tx = threadIdx.x, ty = threadIdx.y;
    if (blk < NTRANS) {
        int cb = (blk % (BATCH / TDIM)) * TDIM;   // batch-col base (mult of 32)
        int rb = (blk / (BATCH / TDIM)) * TDIM;   // var base
#pragma unroll
        for (int j = 0; j < TDIM; j += 8)
            tile[ty + j][tx] = x[(size_t)(rb + ty + j) * BATCH + cb + tx];
        __syncthreads();
        int tid = ty * TDIM + tx;   // 0..255
#pragma unroll
        for (int k = 0; k < 2; ++k) {
            int q = tid + k * 256;          // 512 items = 16 pairs x 32 vars
            int vl = q & 31;                // var-local (fastest -> coalesced)
            int pl = q >> 5;                // pair-local 0..15
            float a = tile[vl][2 * pl];     // col 2p   (bank-conflict-free: 2-way)
            float b = tile[vl][2 * pl + 1]; // col 2p+1
            uint2 val;
            val.x = h2u(__floats2half2_rn(a, b));
            val.y = h2u(__floats2half2_rn(log1mexp_fast(a), log1mexp_fast(b)));
            encE[(size_t)(cb / 2 + pl) * S_U2 + 1 + rb + vl] = val;
        }
        if (rb == 0 && tid < 16)   // header rows {-inf,-inf},{0,0} once per pair
            encE[(size_t)(cb / 2 + tid) * S_U2] = make_uint2(0xFC00FC00u, 0u);
    } else {
        int o = (blk - NTRANS) * 256 + ty * TDIM + tx;
        if (o < N_OUT1) {
            int2 pp = ((const int2*)p1)[o];
            tabB[2 * o]     = ((const int4*)p0)[pp.x];
            tabB[2 * o + 1] = ((const int4*)p0)[pp.y];
        } else {
            int oc = o - N_OUT1;
            int2 pp = ((const int2*)p3)[oc];
            tabC[2 * oc]     = ((const int4*)p2)[pp.x];
            tabC[2 * oc + 1] = ((const int4*)p2)[pp.y];
        }
    }
}

// TWO adjacent batch columns per workgroup. Encode table lives in LDS as
// __half2 (4 B/row -> random ds_read_b32 gathers: uniform 2 lanes/bank = free).
// r1 lives in a SEPARATE f32 LDS region (no overwrite barrier; stores overlap
// later chunks). Tab loads are rolling double-buffered (distance-1 prefetch),
// first chunk issued before the barrier so L2 latency hides under the barrier.
__global__ void __launch_bounds__(TPB, 4)
fused_spn_kernel(const uint2* __restrict__ encE,
                 const int4* __restrict__ tabB,
                 const int4* __restrict__ tabC,
                 float* __restrict__ out) {
    extern __shared__ char smem[];
    const __half2* enc = (const __half2*)smem;         // 8194 rows, dword idx = row
    float2* r1b = (float2*)(smem + ENC_BYTES);         // 8192 float2
    const int bp = blockIdx.x;                          // columns 2*bp, 2*bp+1
    const int t  = threadIdx.x;

    // ---- Phase A: coalesced slab load -> conflict-free strided LDS write
    //      (lane stride 8 B -> uniform 4 requests/bank = pure bandwidth). ----
    const uint2* src = encE + (size_t)bp * S_U2;
    uint2 e0 = src[t], e1 = src[t + 1024], e2 = src[t + 2048], e3 = src[t + 3072];
    // prefetch tab chunk 0 (outputs t, t+1024) — independent of LDS
    int4 a0A = tabB[2 * t],          b0A = tabB[2 * t + 1];
    int4 a1A = tabB[2 * (t + 1024)], b1A = tabB[2 * (t + 1024) + 1];
    {
        uint2* lu2 = (uint2*)smem;
        lu2[t] = e0; lu2[t + 1024] = e1; lu2[t + 2048] = e2; lu2[t + 3072] = e3;
        if (t == 0) lu2[4096] = src[4096];
    }
    __syncthreads();

    // ---- Phase B: 8 outputs/thread, rolling tab prefetch, r1 stored as it
    //      is produced (separate LDS region). ----
    // chunk 1 prefetch
    int4 a0B = tabB[2 * (t + 2048)], b0B = tabB[2 * (t + 2048) + 1];
    int4 a1B = tabB[2 * (t + 3072)], b1B = tabB[2 * (t + 3072) + 1];
    // compute chunk 0
    r1b[t]        = lse2_fast2(gsum_h(enc, a0A), gsum_h(enc, b0A));
    r1b[t + 1024] = lse2_fast2(gsum_h(enc, a1A), gsum_h(enc, b1A));
    // chunk 2 prefetch
    a0A = tabB[2 * (t + 4096)]; b0A = tabB[2 * (t + 4096) + 1];
    a1A = tabB[2 * (t + 5120)]; b1A = tabB[2 * (t + 5120) + 1];
    // compute chunk 1
    r1b[t + 2048] = lse2_fast2(gsum_h(enc, a0B), gsum_h(enc, b0B));
    r1b[t + 3072] = lse2_fast2(gsum_h(enc, a1B), gsum_h(enc, b1B));
    // chunk 3 prefetch
    a0B = tabB[2 * (t + 6144)]; b0B = tabB[2 * (t + 6144) + 1];
    a1B = tabB[2 * (t + 7168)]; b1B = tabB[2 * (t + 7168) + 1];
    // compute chunk 2
    r1b[t + 4096] = lse2_fast2(gsum_h(enc, a0A), gsum_h(enc, b0A));
    r1b[t + 5120] = lse2_fast2(gsum_h(enc, a1A), gsum_h(enc, b1A));
    // Phase-C tab prefetch (hides L2 latency behind chunk 3 + barrier)
    int4 ca0 = tabC[2 * t],          cb0 = tabC[2 * t + 1];
    int4 ca1 = tabC[2 * (t + 1024)], cb1 = tabC[2 * (t + 1024) + 1];
    // compute chunk 3
    r1b[t + 6144] = lse2_fast2(gsum_h(enc, a0B), gsum_h(enc, b0B));
    r1b[t + 7168] = lse2_fast2(gsum_h(enc, a1B), gsum_h(enc, b1B));
    __syncthreads();

    // ---- Phase C: product(4)+lse(2) -> out[o][2bp..2bp+1] (8 B store) ----
    {
        float2 ga = gsum_f(r1b, ca0), gb = gsum_f(r1b, cb0);
        ((float2*)(out + (size_t)t * BATCH))[bp] = lse2_fast2(ga, gb);
        float2 ga1 = gsum_f(r1b, ca1), gb1 = gsum_f(r1b, cb1);
        ((float2*)(out + (size_t)(t + 1024) * BATCH))[bp] = lse2_fast2(ga1, gb1);
    }
}

extern "C" void kernel_launch(void* const* d_in, const int* in_sizes, int n_in,
                              void* d_out, int out_size, void* d_ws, size_t ws_size,
                              hipStream_t stream) {
    const float* x     = (const float*)d_in[0];
    const int*   ptrs0 = (const int*)d_in[1];
    const int*   ptrs1 = (const int*)d_in[3];
    const int*   ptrs2 = (const int*)d_in[5];
    const int*   ptrs3 = (const int*)d_in[7];
    float* out = (float*)d_out;

    uint2* encE = (uint2*)d_ws;                              // 8.4 MB
    int4*  tabB = (int4*)((char*)d_ws + ENC_WS_BYTES);       // 256 KB
    int4*  tabC = tabB + 2 * N_OUT1;                         // 64 KB

    // Allow >64 KB dynamic LDS (gfx950: 160 KB/WG). Unconditional each call.
    hipFuncSetAttribute((const void*)fused_spn_kernel,
                        hipFuncAttributeMaxDynamicSharedMemorySize, SMEM_BYTES);

    prep_kernel<<<NTRANS + NTAB, dim3(32, 8), 0, stream>>>(
        x, encE, ptrs0, ptrs1, ptrs2, ptrs3, tabB, tabC);

    fused_spn_kernel<<<BATCH / 2, TPB, SMEM_BYTES, stream>>>(encE, tabB, tabC, out);
}